// Round 8
// baseline (287.480 us; speedup 1.0000x reference)
//
#include <hip/hip_runtime.h>
#include <stdint.h>
#include <math.h>

typedef uint32_t u32;
typedef uint64_t u64;

#define BB 8
#define CAT 10
#define HW 262144             // 512*512
#define WW 512
#define KSEL 500
#define CHUNKS 32             // scanner WGs per plane
#define CH (HW / CHUNKS)      // 8192 elems per chunk
#define RPB (CAT * CHUNKS)    // 320 regions per batch
#define LCAP 64               // per-region cap (mean 3.3, sigma 1.8 -> 33 sigma)
#define CANDCAP 2048          // per-batch cap (mean 1049, sigma 32)
#define RANKW 8               // ranker WGs per batch
#define THRV 0.9996f
#define NB 4096               // fallback histogram buckets
#define NBQ 16                // NB / 256

// order-preserving float->u32 (ascending)
__device__ __forceinline__ u32 f2u(float f) {
    u32 b = __float_as_uint(f);
    return (b & 0x80000000u) ? ~b : (b | 0x80000000u);
}
__device__ __forceinline__ float u2f(u32 u) {
    u32 b = (u & 0x80000000u) ? (u ^ 0x80000000u) : ~u;
    return __uint_as_float(b);
}
__device__ __forceinline__ int bucketOf(float v) {   // exact monotone (pow2 scale)
    int b = (int)floorf(v * (float)NB);
    return min(max(b, 0), NB - 1);
}

// decode + write one winner at output slot `rank` of batch b
__device__ __forceinline__ void decode_write(int b, int rank, float score, int cls, int ridx,
                                             const float* __restrict__ rot_sine,
                                             const float* __restrict__ rot_cosine,
                                             const float* __restrict__ hei,
                                             const float* __restrict__ dim,
                                             const float* __restrict__ vel,
                                             const float* __restrict__ reg,
                                             float* __restrict__ out) {
    float xs = (float)(ridx % WW);
    float ys = (float)(ridx / WW);
    size_t base = (size_t)b * HW;
    float r0 = reg[((size_t)(b * 2 + 0)) * HW + ridx];
    float r1 = reg[((size_t)(b * 2 + 1)) * HW + ridx];
    float rs = rot_sine[base + ridx];
    float rc = rot_cosine[base + ridx];
    float hg = hei[base + ridx];
    float d0 = dim[((size_t)(b * 3 + 0)) * HW + ridx];
    float d1 = dim[((size_t)(b * 3 + 1)) * HW + ridx];
    float d2 = dim[((size_t)(b * 3 + 2)) * HW + ridx];
    float v0 = vel[((size_t)(b * 2 + 0)) * HW + ridx];
    float v1 = vel[((size_t)(b * 2 + 1)) * HW + ridx];

    float x = (xs + r0) * 0.8f + (-51.2f);
    float y = (ys + r1) * 0.8f + (-51.2f);
    float rot = atan2f(rs, rc);

    size_t obase = ((size_t)b * KSEL + rank) * 9;
    out[obase + 0] = x;
    out[obase + 1] = y;
    out[obase + 2] = hg;
    out[obase + 3] = d0;
    out[obase + 4] = d1;
    out[obase + 5] = d2;
    out[obase + 6] = rot;
    out[obase + 7] = v0;
    out[obase + 8] = v1;

    const int NOUT = BB * KSEL;              // 4000
    out[9 * NOUT + b * KSEL + rank] = score;
    out[10 * NOUT + b * KSEL + rank] = (float)cls;
    bool keep = (x >= -61.2f) && (y >= -61.2f) && (hg >= -10.0f) &&
                (x <= 61.2f) && (y <= 61.2f) && (hg <= 10.0f) &&
                (score > 0.1f);
    out[11 * NOUT + b * KSEL + rank] = keep ? 1.0f : 0.0f;
}

// ---- fallback helpers (256 threads, never taken for this data) ----
__device__ __forceinline__ int find_b1_256(u32* h, u32* ps0, u32* ps1, int* b1_s) {
    const int tid = threadIdx.x;
    u32 p = 0;
#pragma unroll
    for (int q = 0; q < NBQ; ++q) p += h[tid * NBQ + q];
    ps0[tid] = p;
    __syncthreads();
    u32* src = ps0;
    u32* dst = ps1;
    for (int off = 1; off < 256; off <<= 1) {        // suffix scan
        u32 v = src[tid] + ((tid + off < 256) ? src[tid + off] : 0);
        dst[tid] = v;
        __syncthreads();
        u32* t = src; src = dst; dst = t;
    }
    u32 S_t = src[tid];
    u32 S_next = (tid < 255) ? src[tid + 1] : 0;
    if (S_t >= KSEL && (tid == 255 || S_next < KSEL)) {
        u32 run = (tid == 255) ? 0u : S_next;
        int b1 = tid * NBQ;
        for (int q = NBQ - 1; q >= 0; --q) {
            run += h[tid * NBQ + q];
            if (run >= KSEL) { b1 = tid * NBQ + q; break; }
        }
        *b1_s = b1;
    }
    __syncthreads();
    return *b1_s;
}

__device__ __forceinline__ void bitonic_sort_desc_g(u64* cand) {   // global-memory bitonic
    const int tid = threadIdx.x;
    for (int k2 = 2; k2 <= CANDCAP; k2 <<= 1) {
        for (int j = k2 >> 1; j > 0; j >>= 1) {
            for (int i = tid; i < CANDCAP; i += 256) {
                int ixj = i ^ j;
                if (ixj > i) {
                    u64 a = cand[i], b2 = cand[ixj];
                    bool up = ((i & k2) == 0);
                    if ((a < b2) == up) { cand[i] = b2; cand[ixj] = a; }
                }
            }
            __syncthreads();
        }
    }
}

// ---------------- fused scan + decoupled per-batch rank ----------------
__global__ __launch_bounds__(256) void k_all(
        const float* __restrict__ heat,
        const float* __restrict__ rot_sine,
        const float* __restrict__ rot_cosine,
        const float* __restrict__ hei,
        const float* __restrict__ dim,
        const float* __restrict__ vel,
        const float* __restrict__ reg,
        u32* __restrict__ done,          // [BB], zeroed by memset each call
        u32* __restrict__ cnts,
        u64* __restrict__ prebuf,
        u64* __restrict__ gcand,
        u64* __restrict__ gs1k,
        float* __restrict__ out) {
    const int chunk = blockIdx.x;        // 0..CHUNKS-1
    const int bc = blockIdx.y;           // 0..79
    const int tid = threadIdx.x;
    const int b = bc / CAT, c = bc % CAT;
    const int reg_id = c * CHUNKS + chunk;          // 0..319 within batch

    __shared__ __align__(16) char smem[21760];
    u64* keys = (u64*)smem;                         // [2048] 16 KB (rank)
    u64* lbuf = (u64*)(smem + 16384);               // [64]   (scan overlay on cc)
    u32* cc   = (u32*)(smem + 16384);               // [320]
    u32* scA  = (u32*)(smem + 17664);               // [512]
    u32* scB  = (u32*)(smem + 19712);               // [512] -> 21760
    u32* h    = (u32*)smem;                         // fallback overlay [4096]
    u32* ps0  = (u32*)(smem + 17664);               // fallback overlay [256]
    u32* ps1  = (u32*)(smem + 19712);               // fallback overlay [256]
    __shared__ u32 lcnt;
    __shared__ int fb_s, b1_s, cnt_s;

    // ---- phase 1: scan my chunk ----
    if (tid == 0) lcnt = 0;
    __syncthreads();

    const float4* hp = (const float4*)(heat + (size_t)bc * HW + (size_t)chunk * CH);
    const int base_idx = chunk * CH;
#pragma unroll
    for (int it = 0; it < CH / (256 * 4); ++it) {   // 8 float4 loads in flight
        int i4 = it * 256 + tid;
        float4 v = hp[i4];
        float m = fmaxf(fmaxf(v.x, v.y), fmaxf(v.z, v.w));
        if (m > THRV) {                              // rare: ~1 in 600 float4s
            int e0 = base_idx + i4 * 4;
            float vv[4] = {v.x, v.y, v.z, v.w};
#pragma unroll
            for (int j = 0; j < 4; ++j) {
                if (vv[j] > THRV) {
                    u32 pos = atomicAdd(&lcnt, 1u);
                    if (pos < LCAP) {
                        u32 combo = ((u32)c << 18) | (u32)(e0 + j);
                        lbuf[pos] = ((u64)f2u(vv[j]) << 32) | (u32)(0x3FFFFFu - combo);
                    }
                }
            }
        }
    }
    __syncthreads();
    u32 nmine = lcnt;
    u32 nw = nmine > LCAP ? LCAP : nmine;
    if ((u32)tid < nw) prebuf[((size_t)b * RPB + reg_id) * LCAP + tid] = lbuf[tid];
    if (tid == 0) cnts[b * RPB + reg_id] = nmine;    // raw; >LCAP signals overflow
    __threadfence();
    __syncthreads();
    if (tid == 0)
        __hip_atomic_fetch_add(&done[b], 1u, __ATOMIC_ACQ_REL, __HIP_MEMORY_SCOPE_AGENT);

    // ---- only 8 statically-designated ranker WGs per batch continue ----
    if (c != 0 || chunk >= RANKW) return;
    const int rid = chunk;                           // 0..7

    // spin until all 320 scanner WGs of this batch arrived (provably terminates;
    // counters zeroed each call by memset -> poison/replay-immune)
    if (tid == 0) {
        while (__hip_atomic_load(&done[b], __ATOMIC_ACQUIRE, __HIP_MEMORY_SCOPE_AGENT)
               < (u32)RPB)
            __builtin_amdgcn_s_sleep(1);
        fb_s = 0;
    }
    __syncthreads();
    __threadfence();

    // ---- phase 2: counts + prefix scan + validate ----
    for (int i = tid; i < RPB; i += 256) {
        u32 v = cnts[b * RPB + i];
        cc[i] = v;
        if (v > LCAP) fb_s = 1;                      // same-value race OK
    }
    __syncthreads();
    scA[tid] = (tid < RPB) ? cc[tid] : 0;
    scA[tid + 256] = (tid + 256 < RPB) ? cc[tid + 256] : 0;
    __syncthreads();
    u32 *s = scA, *d = scB;
    for (int off = 1; off < 512; off <<= 1) {        // Hillis-Steele inclusive scan
        d[tid] = s[tid] + ((tid >= off) ? s[tid - off] : 0);
        d[tid + 256] = s[tid + 256] + ((tid + 256 >= off) ? s[tid + 256 - off] : 0);
        __syncthreads();
        u32* t = s; s = d; d = t;
    }
    u32 tot = s[RPB - 1];
    if (tid == 0 && (tot < KSEL || tot > CANDCAP)) fb_s = 1;
    __syncthreads();

    if (fb_s == 0) {
        // ---- fast path: gather keys into LDS, rank-count, decode ----
        const int wave = tid >> 6, lane = tid & 63;
        for (int r2 = wave; r2 < RPB; r2 += 4) {     // 80 iters/wave, coalesced
            u32 nr = cc[r2];
            u32 off = s[r2] - nr;                    // exclusive offset
            if ((u32)lane < nr)
                keys[off + lane] = prebuf[((size_t)b * RPB + r2) * LCAP + lane];
        }
        for (int i = (int)tot + tid; i < CANDCAP; i += 256) keys[i] = 0;
        __syncthreads();

        int ci = rid * 256 + tid;                    // this WG's candidate slot
        u64 mk = keys[ci];
        u32 tot4 = (tot + 3) & ~3u;                  // zero-padded -> safe
        u32 r = 0;
        for (u32 j = 0; j < tot4; j += 4) {          // b128-pair broadcast reads
            u64 k0 = keys[j], k1 = keys[j + 1], k2 = keys[j + 2], k3 = keys[j + 3];
            r += (k0 > mk) + (k1 > mk) + (k2 > mk) + (k3 > mk);
        }
        if (ci < (int)tot && r < KSEL) {
            float score = u2f((u32)(mk >> 32));
            u32 combo = 0x3FFFFFu - (u32)(mk & 0xFFFFFFFFull);
            int cls = (int)(combo >> 18);
            int ridx = (int)(combo & 0x3FFFFu);
            decode_write(b, (int)r, score, cls, ridx,
                         rot_sine, rot_cosine, hei, dim, vel, reg, out);
        }
        return;
    }

    // ---- exact fallback: re-scan heat for this batch (never taken; self-sufficient) ----
    if (rid != 0) return;                            // one WG per batch
    u64* cand = gcand + (size_t)b * CANDCAP;
    u64* s1k  = gs1k + (size_t)b * (CAT * KSEL);

    for (int cl = 0; cl < CAT; ++cl) {
        const float* hp2 = heat + (size_t)(b * CAT + cl) * HW;
        for (int i = tid; i < NB; i += 256) h[i] = 0;
        if (tid == 0) cnt_s = 0;
        __syncthreads();
        for (int i = tid; i < HW; i += 256) atomicAdd(&h[bucketOf(hp2[i])], 1u);
        __syncthreads();
        int b1 = find_b1_256(h, ps0, ps1, &b1_s);
        for (int i = tid; i < HW; i += 256) {
            float v = hp2[i];
            if (bucketOf(v) >= b1) {
                int pos = atomicAdd(&cnt_s, 1);
                if (pos < CANDCAP)
                    cand[pos] = ((u64)f2u(v) << 32) | (u32)(~(u32)i);
            }
        }
        __syncthreads();
        int c2 = min(cnt_s, CANDCAP);
        for (int i = c2 + tid; i < CANDCAP; i += 256) cand[i] = 0;
        __syncthreads();
        bitonic_sort_desc_g(cand);
        for (int r2 = tid; r2 < KSEL; r2 += 256) s1k[cl * KSEL + r2] = cand[r2];
        __syncthreads();
    }
    const int NCAND = CAT * KSEL;
    for (int i = tid; i < NB; i += 256) h[i] = 0;
    if (tid == 0) cnt_s = 0;
    __syncthreads();
    for (int i = tid; i < NCAND; i += 256)
        atomicAdd(&h[bucketOf(u2f((u32)(s1k[i] >> 32)))], 1u);
    __syncthreads();
    int b1 = find_b1_256(h, ps0, ps1, &b1_s);
    for (int i = tid; i < NCAND; i += 256) {
        u64 k1 = s1k[i];
        float v = u2f((u32)(k1 >> 32));
        if (bucketOf(v) >= b1) {
            int pos = atomicAdd(&cnt_s, 1);
            if (pos < CANDCAP)
                cand[pos] = (k1 & 0xFFFFFFFF00000000ull) | (u32)(~(u32)i);
        }
    }
    __syncthreads();
    int c2 = min(cnt_s, CANDCAP);
    for (int i = c2 + tid; i < CANDCAP; i += 256) cand[i] = 0;
    __syncthreads();
    bitonic_sort_desc_g(cand);
    for (int r2 = tid; r2 < KSEL; r2 += 256) {
        u64 kk = cand[r2];
        float score = u2f((u32)(kk >> 32));
        int flat = (int)(~(u32)kk);
        int cls = flat / KSEL;
        int ridx = (int)(~(u32)s1k[flat]);
        decode_write(b, r2, score, cls, ridx,
                     rot_sine, rot_cosine, hei, dim, vel, reg, out);
    }
}

extern "C" void kernel_launch(void* const* d_in, const int* in_sizes, int n_in,
                              void* d_out, int out_size, void* d_ws, size_t ws_size,
                              hipStream_t stream) {
    const float* heat       = (const float*)d_in[0];
    const float* rot_sine   = (const float*)d_in[1];
    const float* rot_cosine = (const float*)d_in[2];
    const float* hei        = (const float*)d_in[3];
    const float* dim        = (const float*)d_in[4];
    const float* vel        = (const float*)d_in[5];
    const float* reg        = (const float*)d_in[6];

    char* ws = (char*)d_ws;
    // layout:
    // done    u32[8]          @ 0        (32 B, zeroed each call)
    // cnts    u32[2560]       @ 1024     (10240 B)
    // prebuf  u64[2560*64]    @ 16384    (1310720 B)
    // gcand   u64[8*2048]     @ 1327104  (131072 B, fallback only)
    // gs1k    u64[8*5000]     @ 1458176  (320000 B, fallback only)
    u32* done   = (u32*)ws;
    u32* cnts   = (u32*)(ws + 1024);
    u64* prebuf = (u64*)(ws + 16384);
    u64* gcand  = (u64*)(ws + 1327104);
    u64* gs1k   = (u64*)(ws + 1458176);

    hipMemsetAsync(done, 0, 32, stream);    // poison/replay-proof arrival counters

    k_all<<<dim3(CHUNKS, BB * CAT), 256, 0, stream>>>(
        heat, rot_sine, rot_cosine, hei, dim, vel, reg,
        done, cnts, prebuf, gcand, gs1k, (float*)d_out);
}

// Round 9
// 37.070 us; speedup vs baseline: 7.7550x; 7.7550x over previous
//
#include <hip/hip_runtime.h>
#include <stdint.h>
#include <math.h>

typedef uint32_t u32;
typedef uint64_t u64;

#define BB 8
#define CAT 10
#define HW 262144             // 512*512
#define WW 512
#define KSEL 500
#define CHUNKS 32             // prefilter WGs per plane
#define CH (HW / CHUNKS)      // 8192 elems per chunk
#define NCH (CAT * CHUNKS)    // 320 chunk-regions per batch
#define LCAP 64               // per-chunk candidate capacity (mean 3.3, >20 sigma)
#define CANDCAP 2048          // per-batch candidate capacity (mean 1049, sigma 32)
#define SLICES 16             // k_rank WGs per batch; SLICES*128 == CANDCAP
#define THRV 0.9996f
#define NB 4096               // fallback histogram buckets
#define NBQ 16                // NB / 256

// order-preserving float->u32 (ascending)
__device__ __forceinline__ u32 f2u(float f) {
    u32 b = __float_as_uint(f);
    return (b & 0x80000000u) ? ~b : (b | 0x80000000u);
}
__device__ __forceinline__ float u2f(u32 u) {
    u32 b = (u & 0x80000000u) ? (u ^ 0x80000000u) : ~u;
    return __uint_as_float(b);
}
__device__ __forceinline__ int bucketOf(float v) {   // exact monotone (pow2 scale)
    int b = (int)floorf(v * (float)NB);
    return min(max(b, 0), NB - 1);
}
// combined key: score desc, then (class asc, idx asc); combo < 10*2^18 <= 0x3FFFFF
__device__ __forceinline__ u64 make_key(float v, int c, int idx) {
    u32 combo = ((u32)c << 18) | (u32)idx;
    return ((u64)f2u(v) << 32) | (u32)(0x3FFFFFu - combo);
}

// ---------------- Kernel A: streaming prefilter with forced 8-deep load ILP ----
__global__ __launch_bounds__(256) void k_prefilter(const float* __restrict__ heat,
                                                   u32* __restrict__ cnts,
                                                   u64* __restrict__ prebuf) {
    const int bc = blockIdx.y;       // 0..79
    const int chunk = blockIdx.x;    // 0..CHUNKS-1
    const int tid = threadIdx.x;
    const int c = bc % CAT;
    __shared__ u64 lbuf[LCAP];
    __shared__ u32 lcnt;
    if (tid == 0) lcnt = 0;
    __syncthreads();

    const float4* hp = (const float4*)(heat + (size_t)bc * HW + (size_t)chunk * CH);
    const int base_idx = chunk * CH;

    // Load ALL 8 float4s into live registers, reduce to ONE max, then one rare
    // branch. All 8 global_load_dwordx4 must issue before the combined max ->
    // 8 loads in flight per thread (vs ~2 when the branch sits inside the loop).
    float4 r0 = hp[0 * 256 + tid];
    float4 r1 = hp[1 * 256 + tid];
    float4 r2 = hp[2 * 256 + tid];
    float4 r3 = hp[3 * 256 + tid];
    float4 r4 = hp[4 * 256 + tid];
    float4 r5 = hp[5 * 256 + tid];
    float4 r6 = hp[6 * 256 + tid];
    float4 r7 = hp[7 * 256 + tid];

    float m0 = fmaxf(fmaxf(r0.x, r0.y), fmaxf(r0.z, r0.w));
    float m1 = fmaxf(fmaxf(r1.x, r1.y), fmaxf(r1.z, r1.w));
    float m2 = fmaxf(fmaxf(r2.x, r2.y), fmaxf(r2.z, r2.w));
    float m3 = fmaxf(fmaxf(r3.x, r3.y), fmaxf(r3.z, r3.w));
    float m4 = fmaxf(fmaxf(r4.x, r4.y), fmaxf(r4.z, r4.w));
    float m5 = fmaxf(fmaxf(r5.x, r5.y), fmaxf(r5.z, r5.w));
    float m6 = fmaxf(fmaxf(r6.x, r6.y), fmaxf(r6.z, r6.w));
    float m7 = fmaxf(fmaxf(r7.x, r7.y), fmaxf(r7.z, r7.w));
    float m = fmaxf(fmaxf(fmaxf(m0, m1), fmaxf(m2, m3)),
                    fmaxf(fmaxf(m4, m5), fmaxf(m6, m7)));

    if (m > THRV) {                                  // ~1.3% of threads
        float4 rr[8] = {r0, r1, r2, r3, r4, r5, r6, r7};
#pragma unroll
        for (int k = 0; k < 8; ++k) {
            float vv[4] = {rr[k].x, rr[k].y, rr[k].z, rr[k].w};
            int e0 = base_idx + (k * 256 + tid) * 4;
#pragma unroll
            for (int j = 0; j < 4; ++j) {
                if (vv[j] > THRV) {
                    u32 pos = atomicAdd(&lcnt, 1u);
                    if (pos < LCAP) lbuf[pos] = make_key(vv[j], c, e0 + j);
                }
            }
        }
    }
    __syncthreads();
    u32 nmine = lcnt;
    u32 nw = nmine > LCAP ? LCAP : nmine;
    u64* pb = prebuf + ((size_t)bc * CHUNKS + chunk) * LCAP;
    if ((u32)tid < nw) pb[tid] = lbuf[tid];
    if (tid == 0) cnts[bc * CHUNKS + chunk] = nmine;  // raw; >LCAP signals overflow
}

// ---- fallback helpers (256 threads, never taken for this data) ----
__device__ __forceinline__ int find_b1_256(u32* h, u32* ps0, u32* ps1, int* b1_s) {
    const int tid = threadIdx.x;
    u32 p = 0;
#pragma unroll
    for (int q = 0; q < NBQ; ++q) p += h[tid * NBQ + q];
    ps0[tid] = p;
    __syncthreads();
    u32* src = ps0;
    u32* dst = ps1;
    for (int off = 1; off < 256; off <<= 1) {        // suffix scan
        u32 v = src[tid] + ((tid + off < 256) ? src[tid + off] : 0);
        dst[tid] = v;
        __syncthreads();
        u32* t = src; src = dst; dst = t;
    }
    u32 S_t = src[tid];
    u32 S_next = (tid < 255) ? src[tid + 1] : 0;
    if (S_t >= KSEL && (tid == 255 || S_next < KSEL)) {
        u32 run = (tid == 255) ? 0u : S_next;
        int b1 = tid * NBQ;
        for (int q = NBQ - 1; q >= 0; --q) {
            run += h[tid * NBQ + q];
            if (run >= KSEL) { b1 = tid * NBQ + q; break; }
        }
        *b1_s = b1;
    }
    __syncthreads();
    return *b1_s;
}

__device__ __forceinline__ void bitonic_sort_desc_256(u64* cand) {
    const int tid = threadIdx.x;
    for (int k2 = 2; k2 <= CANDCAP; k2 <<= 1) {
        for (int j = k2 >> 1; j > 0; j >>= 1) {
            for (int i = tid; i < CANDCAP; i += 256) {
                int ixj = i ^ j;
                if (ixj > i) {
                    u64 a = cand[i], b = cand[ixj];
                    bool up = ((i & k2) == 0);
                    if ((a < b) == up) { cand[i] = b; cand[ixj] = a; }
                }
            }
            __syncthreads();
        }
    }
}

// decode + write one winner at output slot `rank` of batch b
__device__ __forceinline__ void decode_write(int b, int rank, float score, int cls, int ridx,
                                             const float* __restrict__ rot_sine,
                                             const float* __restrict__ rot_cosine,
                                             const float* __restrict__ hei,
                                             const float* __restrict__ dim,
                                             const float* __restrict__ vel,
                                             const float* __restrict__ reg,
                                             float* __restrict__ out) {
    float xs = (float)(ridx % WW);
    float ys = (float)(ridx / WW);
    size_t base = (size_t)b * HW;
    float r0 = reg[((size_t)(b * 2 + 0)) * HW + ridx];
    float r1 = reg[((size_t)(b * 2 + 1)) * HW + ridx];
    float rs = rot_sine[base + ridx];
    float rc = rot_cosine[base + ridx];
    float hg = hei[base + ridx];
    float d0 = dim[((size_t)(b * 3 + 0)) * HW + ridx];
    float d1 = dim[((size_t)(b * 3 + 1)) * HW + ridx];
    float d2 = dim[((size_t)(b * 3 + 2)) * HW + ridx];
    float v0 = vel[((size_t)(b * 2 + 0)) * HW + ridx];
    float v1 = vel[((size_t)(b * 2 + 1)) * HW + ridx];

    float x = (xs + r0) * 0.8f + (-51.2f);
    float y = (ys + r1) * 0.8f + (-51.2f);
    float rot = atan2f(rs, rc);

    size_t obase = ((size_t)b * KSEL + rank) * 9;
    out[obase + 0] = x;
    out[obase + 1] = y;
    out[obase + 2] = hg;
    out[obase + 3] = d0;
    out[obase + 4] = d1;
    out[obase + 5] = d2;
    out[obase + 6] = rot;
    out[obase + 7] = v0;
    out[obase + 8] = v1;

    const int NOUT = BB * KSEL;              // 4000
    out[9 * NOUT + b * KSEL + rank] = score;
    out[10 * NOUT + b * KSEL + rank] = (float)cls;
    bool keep = (x >= -61.2f) && (y >= -61.2f) && (hg >= -10.0f) &&
                (x <= 61.2f) && (y <= 61.2f) && (hg <= 10.0f) &&
                (score > 0.1f);
    out[11 * NOUT + b * KSEL + rank] = keep ? 1.0f : 0.0f;
}

// ---------------- Kernel B: rank-count top-k + decode; exact fallback inside ----
__global__ __launch_bounds__(256) void k_rank(const float* __restrict__ heat,
                                              const u32* __restrict__ cnts,
                                              const u64* __restrict__ prebuf,
                                              const float* __restrict__ rot_sine,
                                              const float* __restrict__ rot_cosine,
                                              const float* __restrict__ hei,
                                              const float* __restrict__ dim,
                                              const float* __restrict__ vel,
                                              const float* __restrict__ reg,
                                              float* __restrict__ out) {
    const int b = blockIdx.y;
    const int slice = blockIdx.x;
    const int tid = threadIdx.x;

    __shared__ __align__(16) char smem[77824];          // 76 KB, manually overlaid
    // fast path layout
    u64* keys    = (u64*)smem;                          // [2048] 16 KB
    u32* cc      = (u32*)(smem + 16384);                // [320]
    u32* sc0     = (u32*)(smem + 17920);                // [512]
    u32* sc1     = (u32*)(smem + 19968);                // [512]
    u32* partial = (u32*)(smem + 22016);                // [256]
    // fallback overlay (cc/sc/partial dead once fallback starts)
    u32* h    = (u32*)smem;                             // [4096] 16 KB
    u64* cand = (u64*)(smem + 16384);                   // [2048] 16 KB
    u32* ps0  = (u32*)(smem + 32768);                   // [256]
    u32* ps1  = (u32*)(smem + 33792);                   // [256]
    u64* s1k  = (u64*)(smem + 34816);                   // [5000] 40 KB -> ends 74816
    __shared__ int fb_s;
    __shared__ int b1_s;
    __shared__ int cnt_s;

    if (tid == 0) fb_s = 0;
    __syncthreads();
    const u32* cb = cnts + b * NCH;
    for (int i = tid; i < NCH; i += 256) {
        u32 v = cb[i];
        cc[i] = v;
        if (v > LCAP) fb_s = 1;                         // same-value race OK
    }
    __syncthreads();
    // exclusive prefix over cc via Hillis-Steele inclusive scan of shifted array (512 wide)
    sc0[tid]       = (tid >= 1 && tid - 1 < NCH) ? cc[tid - 1] : 0;
    sc0[tid + 256] = (tid + 255 < NCH) ? cc[tid + 255] : 0;
    __syncthreads();
    u32* src = sc0; u32* dst = sc1;
    for (int off = 1; off < 512; off <<= 1) {
        for (int i = tid; i < 512; i += 256)
            dst[i] = src[i] + ((i >= off) ? src[i - off] : 0);
        __syncthreads();
        u32* t = src; src = dst; dst = t;
    }
    u32 tot = src[NCH];
    if (tid == 0 && (tot < KSEL || tot > CANDCAP)) fb_s = 1;
    __syncthreads();
    int fb = fb_s;

    if (!fb) {
        // ---- fast path: compact keys into LDS, rank-count, scatter by rank ----
        for (int k = tid; k < NCH; k += 256) {
            u32 n = cc[k], off = src[k];
            const u64* pb = prebuf + ((size_t)b * NCH + k) * LCAP;
            for (u32 t = 0; t < n; ++t) keys[off + t] = pb[t];
        }
        for (int i = tid; i < CANDCAP; i += 256)
            if ((u32)i >= tot) keys[i] = 0;             // pad: never outranks real keys
        __syncthreads();

        const int ci  = slice * 128 + (tid & 127);
        const int sub = tid >> 7;                       // wave-uniform
        u64 mk = keys[ci];
        u32 mid = (tot + 1) >> 1;
        u32 j0 = sub ? mid : 0, j1 = sub ? tot : mid;
        u32 r = 0;
#pragma unroll 4
        for (u32 j = j0; j < j1; ++j) r += (keys[j] > mk);   // LDS broadcast reads
        partial[tid] = r;
        __syncthreads();
        if (tid < 128) {
            int rank = (int)(partial[tid] + partial[tid + 128]);
            int cix = slice * 128 + tid;
            if (cix < (int)tot && rank < KSEL) {
                u64 kk = keys[cix];
                float score = u2f((u32)(kk >> 32));
                u32 combo = 0x3FFFFFu - (u32)(kk & 0xFFFFFFFFull);
                int cls = (int)(combo >> 18);
                int ridx = (int)(combo & 0x3FFFFu);
                decode_write(b, rank, score, cls, ridx,
                             rot_sine, rot_cosine, hei, dim, vel, reg, out);
            }
        }
        return;
    }

    // ---- exact fallback (not taken for this data; correctness safety net) ----
    if (slice != 0) return;
    for (int c = 0; c < CAT; ++c) {
        const float* hp = heat + (size_t)(b * CAT + c) * HW;
        for (int i = tid; i < NB; i += 256) h[i] = 0;
        if (tid == 0) cnt_s = 0;
        __syncthreads();
        for (int i = tid; i < HW; i += 256) atomicAdd(&h[bucketOf(hp[i])], 1u);
        __syncthreads();
        int b1 = find_b1_256(h, ps0, ps1, &b1_s);
        for (int i = tid; i < HW; i += 256) {
            float v = hp[i];
            if (bucketOf(v) >= b1) {
                int pos = atomicAdd(&cnt_s, 1);
                if (pos < CANDCAP)
                    cand[pos] = ((u64)f2u(v) << 32) | (u32)(~(u32)i);
            }
        }
        __syncthreads();
        int c2 = min(cnt_s, CANDCAP);
        for (int i = c2 + tid; i < CANDCAP; i += 256) cand[i] = 0;
        __syncthreads();
        bitonic_sort_desc_256(cand);
        for (int r2 = tid; r2 < KSEL; r2 += 256) s1k[c * KSEL + r2] = cand[r2];
        __syncthreads();
    }
    // stage 2 over s1k[5000], tie-break by flat position
    const int NCAND = CAT * KSEL;
    for (int i = tid; i < NB; i += 256) h[i] = 0;
    if (tid == 0) cnt_s = 0;
    __syncthreads();
    for (int i = tid; i < NCAND; i += 256)
        atomicAdd(&h[bucketOf(u2f((u32)(s1k[i] >> 32)))], 1u);
    __syncthreads();
    int b1 = find_b1_256(h, ps0, ps1, &b1_s);
    for (int i = tid; i < NCAND; i += 256) {
        u64 k1 = s1k[i];
        float v = u2f((u32)(k1 >> 32));
        if (bucketOf(v) >= b1) {
            int pos = atomicAdd(&cnt_s, 1);
            if (pos < CANDCAP)
                cand[pos] = (k1 & 0xFFFFFFFF00000000ull) | (u32)(~(u32)i);
        }
    }
    __syncthreads();
    int c2 = min(cnt_s, CANDCAP);
    for (int i = c2 + tid; i < CANDCAP; i += 256) cand[i] = 0;
    __syncthreads();
    bitonic_sort_desc_256(cand);
    for (int r2 = tid; r2 < KSEL; r2 += 256) {
        u64 kk = cand[r2];
        float score = u2f((u32)(kk >> 32));
        int flat = (int)(~(u32)kk);
        int cls = flat / KSEL;
        int ridx = (int)(~(u32)s1k[flat]);
        decode_write(b, r2, score, cls, ridx,
                     rot_sine, rot_cosine, hei, dim, vel, reg, out);
    }
}

extern "C" void kernel_launch(void* const* d_in, const int* in_sizes, int n_in,
                              void* d_out, int out_size, void* d_ws, size_t ws_size,
                              hipStream_t stream) {
    const float* heat       = (const float*)d_in[0];
    const float* rot_sine   = (const float*)d_in[1];
    const float* rot_cosine = (const float*)d_in[2];
    const float* hei        = (const float*)d_in[3];
    const float* dim        = (const float*)d_in[4];
    const float* vel        = (const float*)d_in[5];
    const float* reg        = (const float*)d_in[6];

    char* ws = (char*)d_ws;
    // layout: cnts 80*32*4 = 10240 B | pad to 16384 | prebuf 80*32*64*8 = 1310720 B
    u32* cnts   = (u32*)ws;
    u64* prebuf = (u64*)(ws + 16384);
    // no memset needed: every cnts slot is written unconditionally by k_prefilter

    k_prefilter<<<dim3(CHUNKS, BB * CAT), 256, 0, stream>>>(heat, cnts, prebuf);
    k_rank<<<dim3(SLICES, BB), 256, 0, stream>>>(heat, cnts, prebuf,
                                                 rot_sine, rot_cosine, hei, dim, vel, reg,
                                                 (float*)d_out);
}